// Round 9
// baseline (4437.809 us; speedup 1.0000x reference)
//
#include <hip/hip_runtime.h>
#include <cstdint>
#include <cstddef>

#define DD 128
#define ATS 68    // At row stride: [128 k][64 rows + 4 pad]
#define WTS 130   // epilogue transpose-buffer row stride

// ---------------- CSR build (both graphs in one launch) ----------------

__global__ void count2_k(const int* __restrict__ dstb, const int* __restrict__ dstg,
                         int* __restrict__ degb, int* __restrict__ degg, int E, int gE) {
    int b = blockIdx.x;
    const int* dst = (b < gE) ? dstb : dstg;
    int* deg = (b < gE) ? degb : degg;
    int i = ((b < gE) ? b : b - gE) * blockDim.x + threadIdx.x;
    if (i < E) atomicAdd(&deg[dst[i]], 1);
}

__global__ __launch_bounds__(1024) void scan2_k(const int* __restrict__ degb,
                                                const int* __restrict__ degg,
                                                int* __restrict__ rpb, int* __restrict__ rpg,
                                                int* __restrict__ curb, int* __restrict__ curg,
                                                int n) {
    const int* deg = (blockIdx.x == 0) ? degb : degg;
    int* rp = (blockIdx.x == 0) ? rpb : rpg;
    int* cur = (blockIdx.x == 0) ? curb : curg;
    __shared__ int sums[1024];
    int tid = threadIdx.x;
    int per = (n + 1023) >> 10;
    int start = tid * per;
    int end = min(start + per, n);
    int s = 0;
    for (int i = start; i < end; ++i) s += deg[i];
    sums[tid] = s;
    __syncthreads();
    for (int off = 1; off < 1024; off <<= 1) {
        int v = (tid >= off) ? sums[tid - off] : 0;
        __syncthreads();
        sums[tid] += v;
        __syncthreads();
    }
    int pre = (tid == 0) ? 0 : sums[tid - 1];
    for (int i = start; i < end; ++i) {
        rp[i] = pre;
        cur[i] = pre;
        pre += deg[i];
    }
    if (end == n) rp[n] = pre;
}

__global__ void fill2_k(const int* __restrict__ srcb, const int* __restrict__ dstb,
                        const float* __restrict__ wb,
                        const int* __restrict__ srcg, const int* __restrict__ dstg,
                        const float* __restrict__ wg,
                        int* __restrict__ curb, int* __restrict__ curg,
                        int2* __restrict__ eb, int2* __restrict__ eg, int E, int gE) {
    int b = blockIdx.x;
    bool isb = (b < gE);
    const int* src = isb ? srcb : srcg;
    const int* dst = isb ? dstb : dstg;
    const float* w = isb ? wb : wg;
    int* cur = isb ? curb : curg;
    int2* edges = isb ? eb : eg;
    int i = (isb ? b : b - gE) * blockDim.x + threadIdx.x;
    if (i < E) {
        int d = dst[i];
        int pos = atomicAdd(&cur[d], 1);
        edges[pos] = make_int2(src[i], __float_as_int(w[i]));
    }
}

// ---------------- P = H H^T, S = H + H^T ----------------

__global__ __launch_bounds__(256) void prep_k(const float* __restrict__ H,
                                              float* __restrict__ P,
                                              float* __restrict__ S) {
    int idx = blockIdx.x * 256 + threadIdx.x;
    int i = idx >> 7, j = idx & 127;
    float acc = 0.f;
    for (int k = 0; k < DD; ++k) acc += H[i * DD + k] * H[j * DD + k];
    P[idx] = acc;
    S[idx] = H[i * DD + j] + H[j * DD + i];
}

// ---------------- spmm2: both graphs, interleaved gather chains (unchanged) ----------------

__global__ __launch_bounds__(256, 8) void spmm2_k(
    const int* __restrict__ rpb, const int2* __restrict__ eb,
    const int* __restrict__ rpg, const int2* __restrict__ eg,
    const float* __restrict__ Y,
    float* __restrict__ outb, float* __restrict__ outg, int n)
{
    int node = blockIdx.x * 4 + (threadIdx.x >> 6);
    if (node >= n) return;
    int lane = threadIdx.x & 63;

    int jb = rpb[node], be = rpb[node + 1];
    int jg = rpg[node], ge = rpg[node + 1];
    float b0 = 0.f, b1 = 0.f, g0 = 0.f, g1 = 0.f;

    while (jb + 4 <= be && jg + 4 <= ge) {
        int2 x0 = eb[jb + 0], x1 = eb[jb + 1], x2 = eb[jb + 2], x3 = eb[jb + 3];
        int2 y0 = eg[jg + 0], y1 = eg[jg + 1], y2 = eg[jg + 2], y3 = eg[jg + 3];
        float2 fb0 = *((const float2*)(Y + (size_t)x0.x * DD) + lane);
        float2 fb1 = *((const float2*)(Y + (size_t)x1.x * DD) + lane);
        float2 fb2 = *((const float2*)(Y + (size_t)x2.x * DD) + lane);
        float2 fb3 = *((const float2*)(Y + (size_t)x3.x * DD) + lane);
        float2 fg0 = *((const float2*)(Y + (size_t)y0.x * DD) + lane);
        float2 fg1 = *((const float2*)(Y + (size_t)y1.x * DD) + lane);
        float2 fg2 = *((const float2*)(Y + (size_t)y2.x * DD) + lane);
        float2 fg3 = *((const float2*)(Y + (size_t)y3.x * DD) + lane);
        float wb0 = __int_as_float(x0.y), wb1 = __int_as_float(x1.y);
        float wb2 = __int_as_float(x2.y), wb3 = __int_as_float(x3.y);
        float wg0 = __int_as_float(y0.y), wg1 = __int_as_float(y1.y);
        float wg2 = __int_as_float(y2.y), wg3 = __int_as_float(y3.y);
        b0 += wb0 * fb0.x; b1 += wb0 * fb0.y;
        b0 += wb1 * fb1.x; b1 += wb1 * fb1.y;
        b0 += wb2 * fb2.x; b1 += wb2 * fb2.y;
        b0 += wb3 * fb3.x; b1 += wb3 * fb3.y;
        g0 += wg0 * fg0.x; g1 += wg0 * fg0.y;
        g0 += wg1 * fg1.x; g1 += wg1 * fg1.y;
        g0 += wg2 * fg2.x; g1 += wg2 * fg2.y;
        g0 += wg3 * fg3.x; g1 += wg3 * fg3.y;
        jb += 4; jg += 4;
    }
    while (jb + 4 <= be) {
        int2 x0 = eb[jb + 0], x1 = eb[jb + 1], x2 = eb[jb + 2], x3 = eb[jb + 3];
        float2 f0 = *((const float2*)(Y + (size_t)x0.x * DD) + lane);
        float2 f1 = *((const float2*)(Y + (size_t)x1.x * DD) + lane);
        float2 f2 = *((const float2*)(Y + (size_t)x2.x * DD) + lane);
        float2 f3 = *((const float2*)(Y + (size_t)x3.x * DD) + lane);
        float w0 = __int_as_float(x0.y), w1 = __int_as_float(x1.y);
        float w2 = __int_as_float(x2.y), w3 = __int_as_float(x3.y);
        b0 += w0 * f0.x; b1 += w0 * f0.y;
        b0 += w1 * f1.x; b1 += w1 * f1.y;
        b0 += w2 * f2.x; b1 += w2 * f2.y;
        b0 += w3 * f3.x; b1 += w3 * f3.y;
        jb += 4;
    }
    while (jg + 4 <= ge) {
        int2 y0 = eg[jg + 0], y1 = eg[jg + 1], y2 = eg[jg + 2], y3 = eg[jg + 3];
        float2 f0 = *((const float2*)(Y + (size_t)y0.x * DD) + lane);
        float2 f1 = *((const float2*)(Y + (size_t)y1.x * DD) + lane);
        float2 f2 = *((const float2*)(Y + (size_t)y2.x * DD) + lane);
        float2 f3 = *((const float2*)(Y + (size_t)y3.x * DD) + lane);
        float w0 = __int_as_float(y0.y), w1 = __int_as_float(y1.y);
        float w2 = __int_as_float(y2.y), w3 = __int_as_float(y3.y);
        g0 += w0 * f0.x; g1 += w0 * f0.y;
        g0 += w1 * f1.x; g1 += w1 * f1.y;
        g0 += w2 * f2.x; g1 += w2 * f2.y;
        g0 += w3 * f3.x; g1 += w3 * f3.y;
        jg += 4;
    }
    for (; jb < be; ++jb) {
        int2 e = eb[jb];
        float2 f = *((const float2*)(Y + (size_t)e.x * DD) + lane);
        float wv = __int_as_float(e.y);
        b0 += wv * f.x; b1 += wv * f.y;
    }
    for (; jg < ge; ++jg) {
        int2 e = eg[jg];
        float2 f = *((const float2*)(Y + (size_t)e.x * DD) + lane);
        float wv = __int_as_float(e.y);
        g0 += wv * f.x; g1 += wv * f.y;
    }
    *((float2*)(outb + (size_t)node * DD) + lane) = make_float2(b0, b1);
    *((float2*)(outg + (size_t)node * DD) + lane) = make_float2(g0, g1);
}

// ---------------- dense_vs: vector x scalar GEMM ----------------
// 1024 threads, 64 rows x 128 cols. Wave w owns all 64 rows (lane = row) x 8 cols.
// B-fragments are wave-uniform -> scalar loads, no LDS for B, no per-k barriers.
// acc = X + dg*Y - db*(Y@P1) - dg*(Y@P2) + AbY@S1 + AgY@S2 - AgY
// Yn = (2/3)Y + (1/3)*acc/(db+dg+1)

__global__ __launch_bounds__(1024, 8) void dense_vs_k(
    const float* __restrict__ Yc, const float* __restrict__ X,
    const float* __restrict__ AbY, const float* __restrict__ AgY,
    const float* __restrict__ db, const float* __restrict__ dg,
    const float* __restrict__ P1, const float* __restrict__ P2,
    const float* __restrict__ S1, const float* __restrict__ S2,
    float* __restrict__ Yn, int n)
{
    __shared__ float At[DD * ATS];   // 34816 B; reused as transpose buffer at the end

    const int tid  = threadIdx.x;
    const int lane = tid & 63;                 // = row within tile
    const int wid  = tid >> 6;                 // 0..15
    const int cw   = wid << 3;                 // per-lane copy of col base
    const int c0   = __builtin_amdgcn_readfirstlane(cw);  // provably wave-uniform col base
    const int row0 = blockIdx.x * 64;
    const int rowc = min(row0 + lane, n - 1);

    // stage G^T into At: wave w stages cols cw..cw+7 for all 64 rows (lane = row)
    auto stageT = [&](const float* __restrict__ G) {
        const float* gp = G + (size_t)rowc * DD + cw;
        float4 v0 = *reinterpret_cast<const float4*>(gp);
        float4 v1 = *reinterpret_cast<const float4*>(gp + 4);
        At[(cw + 0) * ATS + lane] = v0.x;
        At[(cw + 1) * ATS + lane] = v0.y;
        At[(cw + 2) * ATS + lane] = v0.z;
        At[(cw + 3) * ATS + lane] = v0.w;
        At[(cw + 4) * ATS + lane] = v1.x;
        At[(cw + 5) * ATS + lane] = v1.y;
        At[(cw + 6) * ATS + lane] = v1.z;
        At[(cw + 7) * ATS + lane] = v1.w;
    };

    const float dbv = db[rowc];
    const float dgv = dg[rowc];

    float acc[8];

    // ---- stage Y ----
    stageT(Yc);
    __syncthreads();

    // ---- init: acc = X + dg*Y ----
    {
        const float* xp = X + (size_t)rowc * DD + c0;
#pragma unroll
        for (int j = 0; j < 8; ++j)
            acc[j] = xp[j] + dgv * At[(c0 + j) * ATS + lane];
    }

    // ---- P-pass: acc -= (db*a)*P1row + (dg*a)*P2row ----
    {
        const float* p1 = P1 + c0;
        const float* p2 = P2 + c0;
#pragma unroll 4
        for (int k = 0; k < DD; ++k) {
            float a = At[k * ATS + lane];
            float am1 = dbv * a;
            float am2 = dgv * a;
            const float* r1 = p1 + k * DD;
            const float* r2 = p2 + k * DD;
#pragma unroll
            for (int j = 0; j < 8; ++j)
                acc[j] -= am1 * r1[j] + am2 * r2[j];
        }
    }

    // ---- S1-pass: acc += AbY @ S1 ----
    __syncthreads();
    stageT(AbY);
    __syncthreads();
    {
        const float* s1 = S1 + c0;
#pragma unroll 4
        for (int k = 0; k < DD; ++k) {
            float a = At[k * ATS + lane];
            const float* r = s1 + k * DD;
#pragma unroll
            for (int j = 0; j < 8; ++j)
                acc[j] += a * r[j];
        }
    }

    // ---- S2-pass: acc += AgY @ S2, then acc -= AgY ----
    __syncthreads();
    stageT(AgY);
    __syncthreads();
    {
        const float* s2 = S2 + c0;
#pragma unroll 4
        for (int k = 0; k < DD; ++k) {
            float a = At[k * ATS + lane];
            const float* r = s2 + k * DD;
#pragma unroll
            for (int j = 0; j < 8; ++j)
                acc[j] += a * r[j];
        }
#pragma unroll
        for (int j = 0; j < 8; ++j)
            acc[j] -= At[(c0 + j) * ATS + lane];
    }

    // ---- epilogue math (row = lane mapping) ----
    {
        const float aq = (1.0f / 3.0f) / (dbv + dgv + 1.0f);
        const float* yp = Yc + (size_t)rowc * DD + c0;
#pragma unroll
        for (int j = 0; j < 8; ++j)
            acc[j] = (2.0f / 3.0f) * yp[j] + acc[j] * aq;
    }

    // ---- transpose through LDS for coalesced store ----
    __syncthreads();
    {
        float* W = At;   // reuse: [64 rows][WTS]
#pragma unroll
        for (int j = 0; j < 8; ++j)
            W[lane * WTS + cw + j] = acc[j];
    }
    __syncthreads();
    {
        const float* W = At;
        int r2 = tid >> 4;             // 0..63
        int c2 = (tid & 15) << 3;      // 0..120
        int row2 = row0 + r2;
        if (row2 < n) {
            float ov[8];
#pragma unroll
            for (int j = 0; j < 8; ++j) ov[j] = W[r2 * WTS + c2 + j];
            float* op = Yn + (size_t)row2 * DD + c2;
            *reinterpret_cast<float4*>(op) = make_float4(ov[0], ov[1], ov[2], ov[3]);
            *reinterpret_cast<float4*>(op + 4) = make_float4(ov[4], ov[5], ov[6], ov[7]);
        }
    }
}

// ---------------- host ----------------

extern "C" void kernel_launch(void* const* d_in, const int* in_sizes, int n_in,
                              void* d_out, int out_size, void* d_ws, size_t ws_size,
                              hipStream_t stream) {
    const float* X   = (const float*)d_in[0];
    const float* H1  = (const float*)d_in[1];
    const float* H2  = (const float*)d_in[2];
    const float* wb  = (const float*)d_in[3];
    const float* wg  = (const float*)d_in[4];
    const float* db  = (const float*)d_in[5];
    const float* dg  = (const float*)d_in[6];
    const int* srcb  = (const int*)d_in[7];
    const int* dstb  = (const int*)d_in[8];
    const int* srcg  = (const int*)d_in[9];
    const int* dstg  = (const int*)d_in[10];
    const int N = in_sizes[5];
    const int E = in_sizes[3];
    float* Yout = (float*)d_out;

    char* p = (char*)d_ws;
    auto alloc = [&](size_t b) -> void* {
        void* r = (void*)p;
        p += (b + 255) & ~(size_t)255;
        return r;
    };
    float* P1 = (float*)alloc((size_t)DD * DD * 4);
    float* S1 = (float*)alloc((size_t)DD * DD * 4);
    float* P2 = (float*)alloc((size_t)DD * DD * 4);
    float* S2 = (float*)alloc((size_t)DD * DD * 4);
    int* degb = (int*)alloc((size_t)N * 4);
    int* degg = (int*)alloc((size_t)N * 4);
    int* rpb  = (int*)alloc((size_t)(N + 1) * 4);
    int* rpg  = (int*)alloc((size_t)(N + 1) * 4);
    int* curb = (int*)alloc((size_t)N * 4);
    int* curg = (int*)alloc((size_t)N * 4);
    int2* eb  = (int2*)alloc((size_t)E * 8);
    int2* eg  = (int2*)alloc((size_t)E * 8);
    float* AbY = (float*)alloc((size_t)N * DD * 4);
    float* AgY = (float*)alloc((size_t)N * DD * 4);
    float* Yw  = (float*)alloc((size_t)N * DD * 4);

    hipMemsetAsync(degb, 0, (size_t)N * 4, stream);
    hipMemsetAsync(degg, 0, (size_t)N * 4, stream);

    int gE = (E + 255) / 256;
    count2_k<<<2 * gE, 256, 0, stream>>>(dstb, dstg, degb, degg, E, gE);
    scan2_k<<<2, 1024, 0, stream>>>(degb, degg, rpb, rpg, curb, curg, N);
    fill2_k<<<2 * gE, 256, 0, stream>>>(srcb, dstb, wb, srcg, dstg, wg,
                                        curb, curg, eb, eg, E, gE);
    prep_k<<<64, 256, 0, stream>>>(H1, P1, S1);
    prep_k<<<64, 256, 0, stream>>>(H2, P2, S2);

    const float* Ycur = X;
    float* Ybufs[2] = {Yw, Yout};
    int gs = (N + 3) / 4;
    int gd = (N + 63) / 64;
    for (int s = 0; s < 8; ++s) {
        float* Yn = Ybufs[s & 1];
        spmm2_k<<<gs, 256, 0, stream>>>(rpb, eb, rpg, eg, Ycur, AbY, AgY, N);
        dense_vs_k<<<gd, 1024, 0, stream>>>(Ycur, X, AbY, AgY, db, dg,
                                            P1, P2, S1, S2, Yn, N);
        Ycur = Yn;
    }
}

// Round 10
// 4200.009 us; speedup vs baseline: 1.0566x; 1.0566x over previous
//
#include <hip/hip_runtime.h>
#include <cstdint>
#include <cstddef>

#define DD 128
#define ATS 68    // At row stride: [128 cols][64 rows + 4 pad]
#define WTS 130   // epilogue transpose-buffer row stride

typedef float f32x8 __attribute__((ext_vector_type(8)));

// ---------------- CSR build (both graphs in one launch) ----------------

__global__ void count2_k(const int* __restrict__ dstb, const int* __restrict__ dstg,
                         int* __restrict__ degb, int* __restrict__ degg, int E, int gE) {
    int b = blockIdx.x;
    const int* dst = (b < gE) ? dstb : dstg;
    int* deg = (b < gE) ? degb : degg;
    int i = ((b < gE) ? b : b - gE) * blockDim.x + threadIdx.x;
    if (i < E) atomicAdd(&deg[dst[i]], 1);
}

__global__ __launch_bounds__(1024) void scan2_k(const int* __restrict__ degb,
                                                const int* __restrict__ degg,
                                                int* __restrict__ rpb, int* __restrict__ rpg,
                                                int* __restrict__ curb, int* __restrict__ curg,
                                                int n) {
    const int* deg = (blockIdx.x == 0) ? degb : degg;
    int* rp = (blockIdx.x == 0) ? rpb : rpg;
    int* cur = (blockIdx.x == 0) ? curb : curg;
    __shared__ int sums[1024];
    int tid = threadIdx.x;
    int per = (n + 1023) >> 10;
    int start = tid * per;
    int end = min(start + per, n);
    int s = 0;
    for (int i = start; i < end; ++i) s += deg[i];
    sums[tid] = s;
    __syncthreads();
    for (int off = 1; off < 1024; off <<= 1) {
        int v = (tid >= off) ? sums[tid - off] : 0;
        __syncthreads();
        sums[tid] += v;
        __syncthreads();
    }
    int pre = (tid == 0) ? 0 : sums[tid - 1];
    for (int i = start; i < end; ++i) {
        rp[i] = pre;
        cur[i] = pre;
        pre += deg[i];
    }
    if (end == n) rp[n] = pre;
}

__global__ void fill2_k(const int* __restrict__ srcb, const int* __restrict__ dstb,
                        const float* __restrict__ wb,
                        const int* __restrict__ srcg, const int* __restrict__ dstg,
                        const float* __restrict__ wg,
                        int* __restrict__ curb, int* __restrict__ curg,
                        int2* __restrict__ eb, int2* __restrict__ eg, int E, int gE) {
    int b = blockIdx.x;
    bool isb = (b < gE);
    const int* src = isb ? srcb : srcg;
    const int* dst = isb ? dstb : dstg;
    const float* w = isb ? wb : wg;
    int* cur = isb ? curb : curg;
    int2* edges = isb ? eb : eg;
    int i = (isb ? b : b - gE) * blockDim.x + threadIdx.x;
    if (i < E) {
        int d = dst[i];
        int pos = atomicAdd(&cur[d], 1);
        edges[pos] = make_int2(src[i], __float_as_int(w[i]));
    }
}

// ---------------- P = H H^T, S = H + H^T (- I optionally) ----------------

__global__ __launch_bounds__(256) void prep_k(const float* __restrict__ H,
                                              float* __restrict__ P,
                                              float* __restrict__ S, int sub_ident) {
    int idx = blockIdx.x * 256 + threadIdx.x;
    int i = idx >> 7, j = idx & 127;
    float acc = 0.f;
    for (int k = 0; k < DD; ++k) acc += H[i * DD + k] * H[j * DD + k];
    P[idx] = acc;
    float s = H[i * DD + j] + H[j * DD + i];
    if (sub_ident && i == j) s -= 1.0f;
    S[idx] = s;
}

// ---------------- aq = (1/3) / (db + dg + 1) ----------------

__global__ void aq_k(const float* __restrict__ db, const float* __restrict__ dg,
                     float* __restrict__ aq, int n) {
    int i = blockIdx.x * blockDim.x + threadIdx.x;
    if (i < n) aq[i] = (1.0f / 3.0f) / (db[i] + dg[i] + 1.0f);
}

// ---------------- denseY: YS1 = Y@S1, YSg = Y@(S2-I), R = X + dg*Y - db*(Y@P1) - dg*(Y@P2) ----------------
// 1024 threads, 64 rows x 128 cols. lane = row; wave w owns cols cw..cw+7.
// B rows are wave-uniform -> scalar loads; single merged k-loop, no inner barriers.

__global__ __launch_bounds__(1024, 2) void denseY_k(
    const float* __restrict__ Yc, const float* __restrict__ X,
    const float* __restrict__ db, const float* __restrict__ dg,
    const float* __restrict__ P1, const float* __restrict__ P2,
    const float* __restrict__ S1, const float* __restrict__ S2m,
    float* __restrict__ YS1, float* __restrict__ YSg, float* __restrict__ R, int n)
{
    __shared__ float At[DD * ATS];   // Y^T tile; reused as transpose buffer at the end

    const int tid  = threadIdx.x;
    const int lane = tid & 63;                 // row within tile
    const int wid  = tid >> 6;                 // 0..15
    const int cw   = wid << 3;
    const int c0   = __builtin_amdgcn_readfirstlane(cw);   // wave-uniform col base
    const int row0 = blockIdx.x * 64;
    const int rowc = min(row0 + lane, n - 1);

    // stage Y^T: wave w stages cols cw..cw+7 for all 64 rows (lane = row)
    {
        const float* gp = Yc + (size_t)rowc * DD + cw;
        float4 v0 = *reinterpret_cast<const float4*>(gp);
        float4 v1 = *reinterpret_cast<const float4*>(gp + 4);
        At[(cw + 0) * ATS + lane] = v0.x;
        At[(cw + 1) * ATS + lane] = v0.y;
        At[(cw + 2) * ATS + lane] = v0.z;
        At[(cw + 3) * ATS + lane] = v0.w;
        At[(cw + 4) * ATS + lane] = v1.x;
        At[(cw + 5) * ATS + lane] = v1.y;
        At[(cw + 6) * ATS + lane] = v1.z;
        At[(cw + 7) * ATS + lane] = v1.w;
    }
    __syncthreads();

    const float dbv = db[rowc];
    const float dgv = dg[rowc];

    float a1[8], a2[8], aR[8];
    // aR init = X + dg*Y
    {
        const float* xp = X + (size_t)rowc * DD + cw;
        float4 x0 = *reinterpret_cast<const float4*>(xp);
        float4 x1 = *reinterpret_cast<const float4*>(xp + 4);
        float xv[8] = {x0.x, x0.y, x0.z, x0.w, x1.x, x1.y, x1.z, x1.w};
#pragma unroll
        for (int j = 0; j < 8; ++j) {
            a1[j] = 0.f; a2[j] = 0.f;
            aR[j] = xv[j] + dgv * At[(c0 + j) * ATS + lane];
        }
    }

    // merged k-loop: 4 wave-uniform B rows (scalar loads) + 1 LDS a-read per k
    {
        const f32x8* pS1 = reinterpret_cast<const f32x8*>(S1 + c0);
        const f32x8* pS2 = reinterpret_cast<const f32x8*>(S2m + c0);
        const f32x8* pP1 = reinterpret_cast<const f32x8*>(P1 + c0);
        const f32x8* pP2 = reinterpret_cast<const f32x8*>(P2 + c0);
#pragma unroll 2
        for (int k = 0; k < DD; ++k) {
            f32x8 b1 = pS1[k * 16];
            f32x8 b2 = pS2[k * 16];
            f32x8 b3 = pP1[k * 16];
            f32x8 b4 = pP2[k * 16];
            float a = At[k * ATS + lane];
            float am1 = dbv * a;
            float am2 = dgv * a;
#pragma unroll
            for (int j = 0; j < 8; ++j) {
                a1[j] += a * b1[j];
                a2[j] += a * b2[j];
                aR[j] -= am1 * b3[j] + am2 * b4[j];
            }
        }
    }

    // ---- write 3 outputs via LDS transpose (coalesced stores) ----
    float* W = At;
    const int r2 = tid >> 4;
    const int c2 = (tid & 15) << 3;
    const int row2 = row0 + r2;

    __syncthreads();   // done reading At(Y)
#pragma unroll
    for (int j = 0; j < 8; ++j) W[lane * WTS + cw + j] = a1[j];
    __syncthreads();
    if (row2 < n) {
        float ov[8];
#pragma unroll
        for (int j = 0; j < 8; ++j) ov[j] = W[r2 * WTS + c2 + j];
        float* op = YS1 + (size_t)row2 * DD + c2;
        *reinterpret_cast<float4*>(op) = make_float4(ov[0], ov[1], ov[2], ov[3]);
        *reinterpret_cast<float4*>(op + 4) = make_float4(ov[4], ov[5], ov[6], ov[7]);
    }
    __syncthreads();
#pragma unroll
    for (int j = 0; j < 8; ++j) W[lane * WTS + cw + j] = a2[j];
    __syncthreads();
    if (row2 < n) {
        float ov[8];
#pragma unroll
        for (int j = 0; j < 8; ++j) ov[j] = W[r2 * WTS + c2 + j];
        float* op = YSg + (size_t)row2 * DD + c2;
        *reinterpret_cast<float4*>(op) = make_float4(ov[0], ov[1], ov[2], ov[3]);
        *reinterpret_cast<float4*>(op + 4) = make_float4(ov[4], ov[5], ov[6], ov[7]);
    }
    __syncthreads();
#pragma unroll
    for (int j = 0; j < 8; ++j) W[lane * WTS + cw + j] = aR[j];
    __syncthreads();
    if (row2 < n) {
        float ov[8];
#pragma unroll
        for (int j = 0; j < 8; ++j) ov[j] = W[r2 * WTS + c2 + j];
        float* op = R + (size_t)row2 * DD + c2;
        *reinterpret_cast<float4*>(op) = make_float4(ov[0], ov[1], ov[2], ov[3]);
        *reinterpret_cast<float4*>(op + 4) = make_float4(ov[4], ov[5], ov[6], ov[7]);
    }
}

// ---------------- spmmF: gather Ab@YS1 + Ag@YSg, fused epilogue ----------------
// Yn = (2/3)*Y + (b + g + R) * aq

__global__ __launch_bounds__(256, 8) void spmmF_k(
    const int* __restrict__ rpb, const int2* __restrict__ eb,
    const int* __restrict__ rpg, const int2* __restrict__ eg,
    const float* __restrict__ YS1, const float* __restrict__ YSg,
    const float* __restrict__ Yc, const float* __restrict__ R,
    const float* __restrict__ aq,
    float* __restrict__ Yn, int n)
{
    int node = blockIdx.x * 4 + (threadIdx.x >> 6);
    if (node >= n) return;
    int lane = threadIdx.x & 63;

    int jb = rpb[node], be = rpb[node + 1];
    int jg = rpg[node], ge = rpg[node + 1];
    float b0 = 0.f, b1 = 0.f, g0 = 0.f, g1 = 0.f;

    while (jb + 4 <= be && jg + 4 <= ge) {
        int2 x0 = eb[jb + 0], x1 = eb[jb + 1], x2 = eb[jb + 2], x3 = eb[jb + 3];
        int2 y0 = eg[jg + 0], y1 = eg[jg + 1], y2 = eg[jg + 2], y3 = eg[jg + 3];
        float2 fb0 = *((const float2*)(YS1 + (size_t)x0.x * DD) + lane);
        float2 fb1 = *((const float2*)(YS1 + (size_t)x1.x * DD) + lane);
        float2 fb2 = *((const float2*)(YS1 + (size_t)x2.x * DD) + lane);
        float2 fb3 = *((const float2*)(YS1 + (size_t)x3.x * DD) + lane);
        float2 fg0 = *((const float2*)(YSg + (size_t)y0.x * DD) + lane);
        float2 fg1 = *((const float2*)(YSg + (size_t)y1.x * DD) + lane);
        float2 fg2 = *((const float2*)(YSg + (size_t)y2.x * DD) + lane);
        float2 fg3 = *((const float2*)(YSg + (size_t)y3.x * DD) + lane);
        float wb0 = __int_as_float(x0.y), wb1 = __int_as_float(x1.y);
        float wb2 = __int_as_float(x2.y), wb3 = __int_as_float(x3.y);
        float wg0 = __int_as_float(y0.y), wg1 = __int_as_float(y1.y);
        float wg2 = __int_as_float(y2.y), wg3 = __int_as_float(y3.y);
        b0 += wb0 * fb0.x; b1 += wb0 * fb0.y;
        b0 += wb1 * fb1.x; b1 += wb1 * fb1.y;
        b0 += wb2 * fb2.x; b1 += wb2 * fb2.y;
        b0 += wb3 * fb3.x; b1 += wb3 * fb3.y;
        g0 += wg0 * fg0.x; g1 += wg0 * fg0.y;
        g0 += wg1 * fg1.x; g1 += wg1 * fg1.y;
        g0 += wg2 * fg2.x; g1 += wg2 * fg2.y;
        g0 += wg3 * fg3.x; g1 += wg3 * fg3.y;
        jb += 4; jg += 4;
    }
    while (jb + 4 <= be) {
        int2 x0 = eb[jb + 0], x1 = eb[jb + 1], x2 = eb[jb + 2], x3 = eb[jb + 3];
        float2 f0 = *((const float2*)(YS1 + (size_t)x0.x * DD) + lane);
        float2 f1 = *((const float2*)(YS1 + (size_t)x1.x * DD) + lane);
        float2 f2 = *((const float2*)(YS1 + (size_t)x2.x * DD) + lane);
        float2 f3 = *((const float2*)(YS1 + (size_t)x3.x * DD) + lane);
        float w0 = __int_as_float(x0.y), w1 = __int_as_float(x1.y);
        float w2 = __int_as_float(x2.y), w3 = __int_as_float(x3.y);
        b0 += w0 * f0.x; b1 += w0 * f0.y;
        b0 += w1 * f1.x; b1 += w1 * f1.y;
        b0 += w2 * f2.x; b1 += w2 * f2.y;
        b0 += w3 * f3.x; b1 += w3 * f3.y;
        jb += 4;
    }
    while (jg + 4 <= ge) {
        int2 y0 = eg[jg + 0], y1 = eg[jg + 1], y2 = eg[jg + 2], y3 = eg[jg + 3];
        float2 f0 = *((const float2*)(YSg + (size_t)y0.x * DD) + lane);
        float2 f1 = *((const float2*)(YSg + (size_t)y1.x * DD) + lane);
        float2 f2 = *((const float2*)(YSg + (size_t)y2.x * DD) + lane);
        float2 f3 = *((const float2*)(YSg + (size_t)y3.x * DD) + lane);
        float w0 = __int_as_float(y0.y), w1 = __int_as_float(y1.y);
        float w2 = __int_as_float(y2.y), w3 = __int_as_float(y3.y);
        g0 += w0 * f0.x; g1 += w0 * f0.y;
        g0 += w1 * f1.x; g1 += w1 * f1.y;
        g0 += w2 * f2.x; g1 += w2 * f2.y;
        g0 += w3 * f3.x; g1 += w3 * f3.y;
        jg += 4;
    }
    for (; jb < be; ++jb) {
        int2 e = eb[jb];
        float2 f = *((const float2*)(YS1 + (size_t)e.x * DD) + lane);
        float wv = __int_as_float(e.y);
        b0 += wv * f.x; b1 += wv * f.y;
    }
    for (; jg < ge; ++jg) {
        int2 e = eg[jg];
        float2 f = *((const float2*)(YSg + (size_t)e.x * DD) + lane);
        float wv = __int_as_float(e.y);
        g0 += wv * f.x; g1 += wv * f.y;
    }

    // fused epilogue
    float2 y = *((const float2*)(Yc + (size_t)node * DD) + lane);
    float2 r = *((const float2*)(R + (size_t)node * DD) + lane);
    float aqv = aq[node];
    float2 o;
    o.x = (2.0f / 3.0f) * y.x + (b0 + g0 + r.x) * aqv;
    o.y = (2.0f / 3.0f) * y.y + (b1 + g1 + r.y) * aqv;
    *((float2*)(Yn + (size_t)node * DD) + lane) = o;
}

// ---------------- host ----------------

extern "C" void kernel_launch(void* const* d_in, const int* in_sizes, int n_in,
                              void* d_out, int out_size, void* d_ws, size_t ws_size,
                              hipStream_t stream) {
    const float* X   = (const float*)d_in[0];
    const float* H1  = (const float*)d_in[1];
    const float* H2  = (const float*)d_in[2];
    const float* wb  = (const float*)d_in[3];
    const float* wg  = (const float*)d_in[4];
    const float* db  = (const float*)d_in[5];
    const float* dg  = (const float*)d_in[6];
    const int* srcb  = (const int*)d_in[7];
    const int* dstb  = (const int*)d_in[8];
    const int* srcg  = (const int*)d_in[9];
    const int* dstg  = (const int*)d_in[10];
    const int N = in_sizes[5];
    const int E = in_sizes[3];
    float* Yout = (float*)d_out;

    char* p = (char*)d_ws;
    auto alloc = [&](size_t b) -> void* {
        void* r = (void*)p;
        p += (b + 255) & ~(size_t)255;
        return r;
    };
    float* P1  = (float*)alloc((size_t)DD * DD * 4);
    float* S1  = (float*)alloc((size_t)DD * DD * 4);
    float* P2  = (float*)alloc((size_t)DD * DD * 4);
    float* S2m = (float*)alloc((size_t)DD * DD * 4);
    int* degb = (int*)alloc((size_t)N * 4);
    int* degg = (int*)alloc((size_t)N * 4);
    int* rpb  = (int*)alloc((size_t)(N + 1) * 4);
    int* rpg  = (int*)alloc((size_t)(N + 1) * 4);
    int* curb = (int*)alloc((size_t)N * 4);
    int* curg = (int*)alloc((size_t)N * 4);
    float* aq = (float*)alloc((size_t)N * 4);
    int2* eb  = (int2*)alloc((size_t)E * 8);
    int2* eg  = (int2*)alloc((size_t)E * 8);
    float* YS1 = (float*)alloc((size_t)N * DD * 4);
    float* YSg = (float*)alloc((size_t)N * DD * 4);
    float* R   = (float*)alloc((size_t)N * DD * 4);
    float* Yw  = (float*)alloc((size_t)N * DD * 4);

    hipMemsetAsync(degb, 0, (size_t)N * 4, stream);
    hipMemsetAsync(degg, 0, (size_t)N * 4, stream);

    int gE = (E + 255) / 256;
    count2_k<<<2 * gE, 256, 0, stream>>>(dstb, dstg, degb, degg, E, gE);
    scan2_k<<<2, 1024, 0, stream>>>(degb, degg, rpb, rpg, curb, curg, N);
    fill2_k<<<2 * gE, 256, 0, stream>>>(srcb, dstb, wb, srcg, dstg, wg,
                                        curb, curg, eb, eg, E, gE);
    prep_k<<<64, 256, 0, stream>>>(H1, P1, S1, 0);
    prep_k<<<64, 256, 0, stream>>>(H2, P2, S2m, 1);
    aq_k<<<(N + 255) / 256, 256, 0, stream>>>(db, dg, aq, N);

    const float* Ycur = X;
    float* Ybufs[2] = {Yw, Yout};
    int gs = (N + 3) / 4;
    int gd = (N + 63) / 64;
    for (int s = 0; s < 8; ++s) {
        float* Yn = Ybufs[s & 1];
        denseY_k<<<gd, 1024, 0, stream>>>(Ycur, X, db, dg, P1, P2, S1, S2m,
                                          YS1, YSg, R, N);
        spmmF_k<<<gs, 256, 0, stream>>>(rpb, eb, rpg, eg, YS1, YSg,
                                        Ycur, R, aq, Yn, N);
        Ycur = Yn;
    }
}